// Round 14
// baseline (7739.529 us; speedup 1.0000x reference)
//
#include <hip/hip_runtime.h>
#include <hip/hip_fp16.h>
#include <math.h>

// DWM recurrent cell. R14: pairwise column-split. Grid = 128 wgs = 64 batches
// x 2 slices. Each wg holds a full LDS replica of its batch's state (replica
// phases, validated R2) but streams only HALF the fp16 weight columns
// (1.08 MB/step/CU vs 2.16 -> halves the per-CU L2-delivery floor).
// Exchange state<->upd via d_ws + device-scope atomic flags (monotonic step
// values, parity double-buffered). No grid.sync.

#define NHEAD 4
#define MSZ   32
#define NADDR 256
#define SEQ   256
#define INDIM 264
#define SU    512
#define DB    256
#define UPDN  424
#define COMBN 904
#define HP    106
#define MEMP  257
#define WTP   257
#define NOCP  75     // padded octo-cols per slice (s0:75, s1:74 active)
#define KSL2  12     // K slices: 10x76 + 2x72 = 904
#define PNOUT 600    // partial stride (s0: 600 outs, s1: 592)

// fp16 weight blob layout in d_ws (half indices)
#define HWS_OFF 0
#define HWO_OFF 462848              // 904*512
#define HWU_OFF 694272              // + 904*256
#define HW_TOT  1077568             // + 904*424
#define PACK_G4 (HW_TOT / 4)
// exchange region (float indices into d_ws)
#define SB0_F   538784              // sbuf [2][64][512]
#define UB0_F   604320              // ubuf [2][64][424]
#define FLAG_BYTE_OFF 2634368      // (UB0_F+2*64*424)*4
#define FLAG_BYTES 16384            // sflag[64*32] + uflag[64*32] uints

// dynamic LDS layout (float offsets)
#define O_MEM    0                  // 8224
#define O_WT     8224               // 1028
#define O_WTDYN  9252               // 1028
#define O_PART   10280              // 12*600=7200 (overlaid by logit/wts)
#define O_COMB   17480              // 904
#define O_STATE  18384              // 512
#define O_READ   18896              // 128
#define O_UPD    19024              // 424
#define O_ERASE  19448              // 128
#define O_KHAT   19576              // 128
#define O_SHIFT  19704              // 12
#define O_JMP    19716              // 12
#define O_JD     19728
#define O_GAMMA  19732
#define O_BETA   19736
#define O_G      19740
#define O_SMAX   19744
#define O_SSUM   19748
#define O_PSUM   19752
#define SMEM_FLOATS 19756           // 79,024 bytes

__device__ __forceinline__ float sigmoidf_(float x) { return 1.0f / (1.0f + expf(-x)); }
__device__ __forceinline__ float softplusf_(float x) { return fmaxf(x, 0.0f) + log1pf(expf(-fabsf(x))); }

__global__ __launch_bounds__(256) void pack_w(
    const float* __restrict__ Ws, const float* __restrict__ Wo,
    const float* __restrict__ Wu, __half* __restrict__ dst)
{
    int g = blockIdx.x * 256 + threadIdx.x;
    if (g >= PACK_G4) return;
    const int T1 = HWO_OFF / 4, T2 = HWU_OFF / 4;
    const float* src; int off;
    if (g < T1)      { src = Ws; off = g * 4; }
    else if (g < T2) { src = Wo; off = (g - T1) * 4; }
    else             { src = Wu; off = (g - T2) * 4; }
    float4 v = *(const float4*)(src + off);
    __half2 a = __floats2half2_rn(v.x, v.y);
    __half2 b = __floats2half2_rn(v.z, v.w);
    *(__half2*)(dst + (size_t)g * 4)     = a;
    *(__half2*)(dst + (size_t)g * 4 + 2) = b;
}

#define FMA8(P, C) { float c_ = (C); \
    float2 f0_ = __half22float2(*(const __half2*)&(P).x); \
    float2 f1_ = __half22float2(*(const __half2*)&(P).y); \
    float2 f2_ = __half22float2(*(const __half2*)&(P).z); \
    float2 f3_ = __half22float2(*(const __half2*)&(P).w); \
    a0 = fmaf(c_, f0_.x, a0); a1 = fmaf(c_, f0_.y, a1); \
    a2 = fmaf(c_, f1_.x, a2); a3 = fmaf(c_, f1_.y, a3); \
    a4 = fmaf(c_, f2_.x, a4); a5 = fmaf(c_, f2_.y, a5); \
    a6 = fmaf(c_, f3_.x, a6); a7 = fmaf(c_, f3_.y, a7); }

__global__ __launch_bounds__(1024, 4) void dwm_kernel(
    const float* __restrict__ xin,
    const __half* __restrict__ hW,
    const float* __restrict__ bo, const float* __restrict__ bs,
    const float* __restrict__ bu,
    float* __restrict__ out,
    float* __restrict__ sbuf,      // [2][64][512]
    float* __restrict__ ubuf,      // [2][64][424]
    unsigned* __restrict__ flags)  // sflag[64*32] then uflag[64*32]
{
    const int blk = blockIdx.x;
    const int b = blk & 63;          // batch
    const int s = blk >> 6;          // slice 0/1 (blk, blk+64 -> same XCD)
    const int tid = threadIdx.x;

    unsigned* sflag = flags;
    unsigned* uflag = flags + 64 * 32;
    unsigned* myflag = (s ? uflag : sflag) + b * 32;
    unsigned* wflag  = (s ? sflag : uflag) + b * 32;

    extern __shared__ float smem[];
    float* s_mem   = smem + O_MEM;
    float* s_wt    = smem + O_WT;
    float* s_wtdyn = smem + O_WTDYN;
    float* s_part  = smem + O_PART;
    float* s_logit = smem + O_PART;          // overlays s_part
    float* s_wts   = smem + O_PART + 1028;
    float* s_comb  = smem + O_COMB;
    float* s_state = smem + O_STATE;
    float* s_read  = smem + O_READ;
    float* s_upd   = smem + O_UPD;
    float* s_erase = smem + O_ERASE;
    float* s_khat  = smem + O_KHAT;
    float* s_shift = smem + O_SHIFT;
    float* s_jmp   = smem + O_JMP;
    float* s_jd    = smem + O_JD;
    float* s_gamma = smem + O_GAMMA;
    float* s_beta  = smem + O_BETA;
    float* s_g     = smem + O_G;
    float* s_smax  = smem + O_SMAX;
    float* s_ssum  = smem + O_SSUM;
    float* s_psum  = smem + O_PSUM;

    // ---- init carry (identical replicas) ----
    if (tid < SU) s_state[tid] = 1.0f;
    {
        int h = tid >> 8, n = tid & 255;
        float v = (n == 0) ? 1.0f : 0.0f;
        s_wt[h * WTP + n] = v;
        s_wtdyn[h * WTP + n] = v;
    }
    for (int idx = tid; idx < MSZ * NADDR; idx += 1024) {
        int m = idx >> 8, n = idx & 255;
        s_mem[m * MEMP + n] = 0.01f;
    }
    __syncthreads();

    // ---- matvec decode: tid = ks*75 + ocl; global oc = s*75 + ocl ----
    const int mv_ks  = tid / NOCP;          // 0..13, active if <12
    const int mv_ocl = tid - mv_ks * NOCP;  // 0..74
    const int mv_ocg = s * 75 + mv_ocl;
    const bool mv_act = (mv_ks < KSL2) && (mv_ocg < 149);
    const int mv_k0  = (mv_ks < 10) ? 76 * mv_ks : 760 + 72 * (mv_ks - 10);
    const int mv_nit = (mv_ks < 10) ? 19 : 18;      // quad-row iters (rows = 4*nit)
    const __half* mv_W; int mv_ncol, mv_c;
    if (mv_ocg < 64)      { mv_W = hW + HWS_OFF; mv_ncol = SU;   mv_c = mv_ocg * 8; }
    else if (mv_ocg < 96) { mv_W = hW + HWO_OFF; mv_ncol = DB;   mv_c = (mv_ocg - 64) * 8; }
    else                  { mv_W = hW + HWU_OFF; mv_ncol = UPDN; mv_c = (mv_ocg - 96) * 8; }

    const int NOUTs = PNOUT - s * 8;        // 600 / 592

    for (int t = 0; t < SEQ; ++t) {
        const int p = t & 1;

        // ---- A: read[h][m] = sum_n wt[h][n] * mem[m][n] (bank-spread m) ----
        {
            int pair = tid >> 3, sub = tid & 7;
            int h = pair >> 5, pp = pair & 31;
            int m = ((pp & 7) << 2) | (pp >> 3);
            float pv = 0.0f;
            #pragma unroll 8
            for (int k = 0; k < 32; ++k) {
                int n = sub + (k << 3);
                pv = fmaf(s_wt[h * WTP + n], s_mem[m * MEMP + n], pv);
            }
            pv += __shfl_down(pv, 4);
            pv += __shfl_down(pv, 2);
            pv += __shfl_down(pv, 1);
            if (sub == 0) s_read[h * MSZ + m] = pv;
        }
        __syncthreads();

        // ---- B: comb = [x_t | state | read] ----
        if (tid < INDIM)              s_comb[tid] = xin[((size_t)b * SEQ + t) * INDIM + tid];
        else if (tid < INDIM + SU)    s_comb[tid] = (t == 0) ? 1.0f : s_state[tid - INDIM];
        else if (tid < COMBN)         s_comb[tid] = s_read[tid - (INDIM + SU)];
        __syncthreads();

        // ---- C: matvec over this slice's 8-col groups, uint4 + 4-row prefetch ----
        if (mv_act) {
            const __half* wp = mv_W + (size_t)mv_k0 * mv_ncol + mv_c;
            const int stride = mv_ncol;
            float a0=0.f,a1=0.f,a2=0.f,a3=0.f,a4=0.f,a5=0.f,a6=0.f,a7=0.f;
            uint4 p0 = *(const uint4*)(wp);
            uint4 p1 = *(const uint4*)(wp + stride);
            uint4 p2 = *(const uint4*)(wp + 2 * stride);
            uint4 p3 = *(const uint4*)(wp + 3 * stride);
            wp += 4 * stride;
            int k = mv_k0;
            for (int it = 0; it < mv_nit - 1; ++it) {
                uint4 n0 = *(const uint4*)(wp);
                uint4 n1 = *(const uint4*)(wp + stride);
                uint4 n2 = *(const uint4*)(wp + 2 * stride);
                uint4 n3 = *(const uint4*)(wp + 3 * stride);
                wp += 4 * stride;
                float4 cb = *(const float4*)&s_comb[k];
                FMA8(p0, cb.x); FMA8(p1, cb.y); FMA8(p2, cb.z); FMA8(p3, cb.w);
                k += 4;
                p0 = n0; p1 = n1; p2 = n2; p3 = n3;
            }
            float4 cb = *(const float4*)&s_comb[k];
            FMA8(p0, cb.x); FMA8(p1, cb.y); FMA8(p2, cb.z); FMA8(p3, cb.w);
            float* dst = s_part + mv_ks * PNOUT + mv_ocl * 8;
            *(float4*)dst       = make_float4(a0, a1, a2, a3);
            *(float4*)(dst + 4) = make_float4(a4, a5, a6, a7);
        }
        __syncthreads();

        // ---- D: reduce 12 partials + bias + act; route; publish to partner ----
        if (tid < NOUTs) {
            float sm = 0.0f;
            #pragma unroll
            for (int ks = 0; ks < KSL2; ++ks) sm += s_part[ks * PNOUT + tid];
            int vg = s * PNOUT + tid;
            if (vg < SU) {
                float val = sigmoidf_(sm + bs[vg]);
                s_state[vg] = val;
                sbuf[((size_t)p * 64 + b) * SU + vg] = val;
            } else if (vg < SU + DB) {
                int c = vg - SU;
                out[((size_t)b * SEQ + t) * DB + c] = sigmoidf_(sm + bo[c]);
            } else {
                int c = vg - (SU + DB);
                float val = sm + bu[c];
                s_upd[c] = val;
                ubuf[((size_t)p * 64 + b) * UPDN + c] = val;
            }
        }
        __syncthreads();            // drains vmem stores before flag

        if (t == SEQ - 1) break;    // both slices break pre-publish: no wait

        // ---- E: publish own flag, wait partner, pull payload ----
        if (tid == 0) {
            __threadfence();                         // release (wb L2)
            atomicExch(myflag, (unsigned)(t + 1));
            while (atomicAdd(wflag, 0u) < (unsigned)(t + 1))
                __builtin_amdgcn_s_sleep(2);
            __threadfence();                         // acquire (inv caches)
        }
        __syncthreads();
        if (s == 0) { if (tid < UPDN) s_upd[tid]   = ubuf[((size_t)p * 64 + b) * UPDN + tid]; }
        else        { if (tid < SU)   s_state[tid] = sbuf[((size_t)p * 64 + b) * SU + tid]; }
        __syncthreads();

        // ---- F: per-head parameter transforms ----
        if (tid < NHEAD * MSZ) {
            int h = tid >> 5, e = tid & 31;
            const float* uu = &s_upd[h * HP];
            s_erase[h * MSZ + e] = sigmoidf_(uu[8 + e]);
            float kv = tanhf(uu[72 + e]);
            float ss = kv * kv;
            ss += __shfl_xor(ss, 1);
            ss += __shfl_xor(ss, 2);
            ss += __shfl_xor(ss, 4);
            ss += __shfl_xor(ss, 8);
            ss += __shfl_xor(ss, 16);
            s_khat[h * MSZ + e] = kv / (sqrtf(ss) + 1e-12f);
        }
        if (tid < NHEAD) {
            const float* uu = &s_upd[tid * HP];
            float a0 = softplusf_(uu[0]), a1 = softplusf_(uu[1]), a2 = softplusf_(uu[2]);
            float mx = fmaxf(a0, fmaxf(a1, a2));
            float e0 = expf(a0 - mx), e1 = expf(a1 - mx), e2 = expf(a2 - mx);
            float inv = 1.0f / (e0 + e1 + e2);
            s_shift[tid * 3 + 0] = e0 * inv;
            s_shift[tid * 3 + 1] = e1 * inv;
            s_shift[tid * 3 + 2] = e2 * inv;
            s_jd[tid] = sigmoidf_(uu[3]);
            float j0 = uu[4], j1 = uu[5], j2 = uu[6];
            float jm = fmaxf(j0, fmaxf(j1, j2));
            float f0 = expf(j0 - jm), f1 = expf(j1 - jm), f2 = expf(j2 - jm);
            float jinv = 1.0f / (f0 + f1 + f2);
            s_jmp[tid * 3 + 0] = f0 * jinv;
            s_jmp[tid * 3 + 1] = f1 * jinv;
            s_jmp[tid * 3 + 2] = f2 * jinv;
            s_gamma[tid] = 1.0f + softplusf_(uu[7]);
            s_beta[tid] = softplusf_(uu[104]);
            s_g[tid] = sigmoidf_(uu[105]);
        }
        __syncthreads();

        // ---- G: memory erase/add (uses OLD wt) ----
        #pragma unroll
        for (int r = 0; r < 8; ++r) {
            int idx = tid + (r << 10);
            int m = idx >> 8, n = idx & 255;
            float w0 = s_wt[0 * WTP + n], w1 = s_wt[1 * WTP + n];
            float w2 = s_wt[2 * WTP + n], w3 = s_wt[3 * WTP + n];
            float prod = (1.0f - s_erase[0 * MSZ + m] * w0) * (1.0f - s_erase[1 * MSZ + m] * w1)
                       * (1.0f - s_erase[2 * MSZ + m] * w2) * (1.0f - s_erase[3 * MSZ + m] * w3);
            float addv = s_upd[0 * HP + 40 + m] * w0 + s_upd[1 * HP + 40 + m] * w1
                       + s_upd[2 * HP + 40 + m] * w2 + s_upd[3 * HP + 40 + m] * w3;
            s_mem[m * MEMP + n] = s_mem[m * MEMP + n] * prod + addv;
        }
        __syncthreads();

        // ---- H: content logits with fused column norm ----
        {
            int h = tid >> 8, n = tid & 255;
            float ss = 0.0f, d = 0.0f;
            #pragma unroll 8
            for (int m = 0; m < MSZ; ++m) {
                float v = s_mem[m * MEMP + n];
                ss = fmaf(v, v, ss);
                d = fmaf(s_khat[h * MSZ + m], v, d);
            }
            s_logit[h * WTP + n] = s_beta[h] * d / (sqrtf(ss) + 1e-12f);
        }
        __syncthreads();

        // ---- I: per-head softmax reduce ----
        if (tid < 256) {
            int h = tid >> 6, lane = tid & 63;
            float mx = -1e30f;
            #pragma unroll
            for (int k = 0; k < 4; ++k) mx = fmaxf(mx, s_logit[h * WTP + lane + (k << 6)]);
            for (int m2 = 32; m2 >= 1; m2 >>= 1) mx = fmaxf(mx, __shfl_xor(mx, m2));
            float sm = 0.0f;
            #pragma unroll
            for (int k = 0; k < 4; ++k) sm += expf(s_logit[h * WTP + lane + (k << 6)] - mx);
            for (int m2 = 32; m2 >= 1; m2 >>= 1) sm += __shfl_xor(sm, m2);
            if (lane == 0) { s_smax[h] = mx; s_ssum[h] = sm; }
        }
        __syncthreads();

        // ---- J: gate (recomputed 3x, fused) + circular conv + sharpen ----
        {
            int h = tid >> 8, n = tid & 255;
            float gg = s_g[h], om = 1.0f - gg;
            float inv = 1.0f / s_ssum[h], mx = s_smax[h];
            int nm = (n + 255) & 255, np = (n + 1) & 255;
            float wgm = gg * expf(s_logit[h * WTP + nm] - mx) * inv + om * s_wt[h * WTP + nm];
            float wg0 = gg * expf(s_logit[h * WTP + n ] - mx) * inv + om * s_wt[h * WTP + n ];
            float wgp = gg * expf(s_logit[h * WTP + np] - mx) * inv + om * s_wt[h * WTP + np];
            float v = s_shift[h * 3 + 0] * wgm + s_shift[h * 3 + 1] * wg0 + s_shift[h * 3 + 2] * wgp;
            s_wts[h * WTP + n] = powf(v + 1e-12f, s_gamma[h]);
        }
        __syncthreads();

        // ---- K: sharpen-normalizer reduce ----
        if (tid < 256) {
            int h = tid >> 6, lane = tid & 63;
            float sm = 0.0f;
            #pragma unroll
            for (int k = 0; k < 4; ++k) sm += s_wts[h * WTP + lane + (k << 6)];
            for (int m2 = 32; m2 >= 1; m2 >>= 1) sm += __shfl_xor(sm, m2);
            if (lane == 0) s_psum[h] = sm;
        }
        __syncthreads();

        // ---- L: snapshot + jump; new wt, wt_dyn ----
        {
            int h = tid >> 8, n = tid & 255;
            float ws_ = s_wts[h * WTP + n] / s_psum[h];
            float jd = s_jd[h];
            float dyn = (1.0f - jd) * s_wtdyn[h * WTP + n] + jd * ws_;
            s_wtdyn[h * WTP + n] = dyn;
            float w0v = (n == 0) ? 1.0f : 0.0f;
            s_wt[h * WTP + n] = s_jmp[h * 3 + 0] * ws_ + s_jmp[h * 3 + 1] * dyn + s_jmp[h * 3 + 2] * w0v;
        }
        __syncthreads();
    }
}

extern "C" void kernel_launch(void* const* d_in, const int* in_sizes, int n_in,
                              void* d_out, int out_size, void* d_ws, size_t ws_size,
                              hipStream_t stream) {
    const float* x  = (const float*)d_in[0];
    const float* Wo = (const float*)d_in[1];
    const float* bo = (const float*)d_in[2];
    const float* Ws = (const float*)d_in[3];
    const float* bs = (const float*)d_in[4];
    const float* Wu = (const float*)d_in[5];
    const float* bu = (const float*)d_in[6];
    float* outp = (float*)d_out;
    __half* hW = (__half*)d_ws;
    float* sbuf = (float*)d_ws + SB0_F;
    float* ubuf = (float*)d_ws + UB0_F;
    unsigned* flags = (unsigned*)((char*)d_ws + FLAG_BYTE_OFF);

    hipMemsetAsync((char*)d_ws + FLAG_BYTE_OFF, 0, FLAG_BYTES, stream);
    int pack_blocks = (PACK_G4 + 255) / 256;
    hipLaunchKernelGGL(pack_w, dim3(pack_blocks), dim3(256), 0, stream, Ws, Wo, Wu, hW);

    void* args[] = { (void*)&x, (void*)&hW, (void*)&bo, (void*)&bs, (void*)&bu,
                     (void*)&outp, (void*)&sbuf, (void*)&ubuf, (void*)&flags };
    hipLaunchCooperativeKernel((const void*)dwm_kernel, dim3(128), dim3(1024),
                               args, SMEM_FLOATS * 4, stream);
}